// Round 1
// baseline (201.057 us; speedup 1.0000x reference)
//
#include <hip/hip_runtime.h>
#include <math.h>

#define RSQ 0.99999500003749975f  // 1/sqrt(1+1e-5)

// ---------------------------------------------------------------------------
// Kernel 1: CoordPooling. One block per (b,c) 64x64 plane.
// y_pre[bc][0:64]  = mean over w (per h)   (matches x.mean(axis=3))
// y_pre[bc][64:128]= mean over h (per w)   (matches x.mean(axis=2))
// ---------------------------------------------------------------------------
__global__ __launch_bounds__(256) void kpool(const float* __restrict__ x,
                                             float* __restrict__ yp) {
    __shared__ float pl[4096];
    __shared__ float part[256];
    int bc = blockIdx.x;
    int t = threadIdx.x;
    const float4* xp = reinterpret_cast<const float4*>(x) + (size_t)bc * 1024;
    float4* pl4 = reinterpret_cast<float4*>(pl);
#pragma unroll
    for (int k = 0; k < 4; ++k) pl4[k * 256 + t] = xp[k * 256 + t];
    __syncthreads();
    int lane = t & 63, pt = t >> 6;
    // row sums: rotate w by lane to avoid same-bank stride-64 reads
    float rs = 0.f;
#pragma unroll
    for (int j = 0; j < 16; ++j) {
        int w = (pt * 16 + j + lane) & 63;
        rs += pl[lane * 64 + w];
    }
    part[t] = rs;
    __syncthreads();
    if (t < 64) {
        float v = part[t] + part[t + 64] + part[t + 128] + part[t + 192];
        yp[(size_t)bc * 128 + t] = v * 0.015625f;
    }
    __syncthreads();
    // col sums: naturally conflict-free (lanes read consecutive w)
    float cs = 0.f;
#pragma unroll
    for (int j = 0; j < 16; ++j) {
        cs += pl[(pt * 16 + j) * 64 + lane];
    }
    part[t] = cs;
    __syncthreads();
    if (t < 64) {
        float v = part[t] + part[t + 64] + part[t + 128] + part[t + 192];
        yp[(size_t)bc * 128 + 64 + t] = v * 0.015625f;
    }
}

// ---------------------------------------------------------------------------
// Kernels 2&3: CBR 1x1 conv as tiled GEMM.
// out[b,o,l] = relu( (sum_c W[o,c]*in[b,c,l]) * g[o]*RSQ + bias[o] )
// Block tile: 64 o x 32 l. grid = (6 otiles, 4 ltiles, 32 b). 512 threads.
// ltile>=2 selects the second weight set (for the xh/xw pass; pass the same
// set twice for the y pass).
// ---------------------------------------------------------------------------
__global__ __launch_bounds__(512) void kcbr(const float* __restrict__ in,
    const float* __restrict__ W0, const float* __restrict__ g0, const float* __restrict__ b0,
    const float* __restrict__ W1, const float* __restrict__ g1, const float* __restrict__ b1,
    float* __restrict__ out) {
    __shared__ float Wl[32][68];   // [cc][o_rel], pad 68 => 16B-aligned rows, low write conflicts
    __shared__ float Yl[32][32];   // [cc][l]
    int o0 = blockIdx.x * 64;
    int lt = blockIdx.y;
    int b  = blockIdx.z;
    int l0 = lt * 32;
    const float* W  = (lt >= 2) ? W1 : W0;
    const float* g  = (lt >= 2) ? g1 : g0;
    const float* bb = (lt >= 2) ? b1 : b0;
    int t = threadIdx.x;
    int li = t & 31, og = t >> 5;  // og in [0,16): 4 consecutive o's per thread
    float acc0 = 0.f, acc1 = 0.f, acc2 = 0.f, acc3 = 0.f;
    const float* inb = in + (size_t)b * 384 * 128 + l0;
    for (int c0 = 0; c0 < 384; c0 += 32) {
#pragma unroll
        for (int i = 0; i < 4; ++i) {
            int e = t + i * 512;
            int cc = e & 31, orel = e >> 5;
            Wl[cc][orel] = W[(size_t)(o0 + orel) * 384 + c0 + cc];
        }
#pragma unroll
        for (int i = 0; i < 2; ++i) {
            int e = t + i * 512;
            int ll = e & 31, cc = e >> 5;
            Yl[cc][ll] = inb[(size_t)(c0 + cc) * 128 + ll];
        }
        __syncthreads();
#pragma unroll
        for (int cc = 0; cc < 32; ++cc) {
            float yv = Yl[cc][li];
            const float4 wv = *reinterpret_cast<const float4*>(&Wl[cc][og * 4]);
            acc0 = fmaf(wv.x, yv, acc0);
            acc1 = fmaf(wv.y, yv, acc1);
            acc2 = fmaf(wv.z, yv, acc2);
            acc3 = fmaf(wv.w, yv, acc3);
        }
        __syncthreads();
    }
    int o = o0 + og * 4;
    size_t ob = ((size_t)b * 384 + o) * 128 + l0 + li;
    out[ob]       = fmaxf(fmaf(acc0, g[o]     * RSQ, bb[o]),     0.f);
    out[ob + 128] = fmaxf(fmaf(acc1, g[o + 1] * RSQ, bb[o + 1]), 0.f);
    out[ob + 256] = fmaxf(fmaf(acc2, g[o + 2] * RSQ, bb[o + 2]), 0.f);
    out[ob + 384] = fmaxf(fmaf(acc3, g[o + 3] * RSQ, bb[o + 3]), 0.f);
}

// ---------------------------------------------------------------------------
// Kernel 4: wavelet (== scaled channel mean) + FC->BN->ReLU->FC. One block/b.
// z0[c] = mean_l y[b,c,l] * 2^(i/2), i = 1 + c/128
// z1[r] = relu((z0 @ fc0_w[r] + fc0_b[r]) * bn1_g[r]*RSQ + bn1_b[r])
// z2[c] = z1 @ fc1_w[c] + fc1_b[c]
// ---------------------------------------------------------------------------
__global__ __launch_bounds__(256) void kgate(const float* __restrict__ y,
    const float* __restrict__ fc0_w, const float* __restrict__ fc0_b,
    const float* __restrict__ bn1_g, const float* __restrict__ bn1_b,
    const float* __restrict__ fc1_w, const float* __restrict__ fc1_b,
    float* __restrict__ z2) {
    __shared__ float z0[384];
    __shared__ float z1[24];
    int b = blockIdx.x;
    int t = threadIdx.x;
    const float* yb = y + (size_t)b * 384 * 128;
    for (int c = t; c < 384; c += 256) {
        float s = 0.f;
        const float* row = yb + (size_t)c * 128;
#pragma unroll 8
        for (int l = 0; l < 128; ++l) s += row[l];
        float fac = (c < 128) ? 1.41421356237310f : (c < 256 ? 2.0f : 2.82842712474619f);
        z0[c] = s * (fac * 0.0078125f);  // /128
    }
    __syncthreads();
    if (t < 192) {
        int r = t >> 3, j = t & 7;
        float p = 0.f;
        for (int c = j; c < 384; c += 8) p = fmaf(z0[c], fc0_w[r * 384 + c], p);
        p += __shfl_xor(p, 1);
        p += __shfl_xor(p, 2);
        p += __shfl_xor(p, 4);
        if (j == 0) {
            float v = fmaf(p + fc0_b[r], bn1_g[r] * RSQ, bn1_b[r]);
            z1[r] = fmaxf(v, 0.f);
        }
    }
    __syncthreads();
    for (int c = t; c < 384; c += 256) {
        float a = fc1_b[c];
#pragma unroll
        for (int r = 0; r < 24; ++r) a = fmaf(z1[r], fc1_w[c * 24 + r], a);
        z2[b * 384 + c] = a;
    }
}

// ---------------------------------------------------------------------------
// Kernel 5: out = x * (sigmoid(xh[b,c,h]*xw[b,c,w]) + z2[b,c])
// hw buffer layout: [b][c][128], first 64 = xh row, last 64 = xw row.
// ---------------------------------------------------------------------------
__global__ __launch_bounds__(256) void kfinal(const float* __restrict__ x,
    const float* __restrict__ hw, const float* __restrict__ z2,
    float* __restrict__ out) {
    const float4* x4 = reinterpret_cast<const float4*>(x);
    float4* o4 = reinterpret_cast<float4*>(out);
    const int total4 = 12582912;  // 32*384*64*64/4
    int stride = gridDim.x * blockDim.x;
    for (int idx = blockIdx.x * blockDim.x + threadIdx.x; idx < total4; idx += stride) {
        int w4 = idx & 15;
        int h  = (idx >> 4) & 63;
        int bc = idx >> 10;
        float4 xv = x4[idx];
        float  a  = hw[(bc << 7) + h];
        const float4 wv = reinterpret_cast<const float4*>(hw)[(bc << 5) + 16 + w4];
        float  zv = z2[bc];
        float4 ov;
        ov.x = xv.x * (1.f / (1.f + __expf(-a * wv.x)) + zv);
        ov.y = xv.y * (1.f / (1.f + __expf(-a * wv.y)) + zv);
        ov.z = xv.z * (1.f / (1.f + __expf(-a * wv.z)) + zv);
        ov.w = xv.w * (1.f / (1.f + __expf(-a * wv.w)) + zv);
        o4[idx] = ov;
    }
}

// ---------------------------------------------------------------------------
extern "C" void kernel_launch(void* const* d_in, const int* in_sizes, int n_in,
                              void* d_out, int out_size, void* d_ws, size_t ws_size,
                              hipStream_t stream) {
    const float* x     = (const float*)d_in[0];
    const float* Wy    = (const float*)d_in[1];
    const float* gy    = (const float*)d_in[2];
    const float* by    = (const float*)d_in[3];
    const float* Wh    = (const float*)d_in[4];
    const float* gh    = (const float*)d_in[5];
    const float* bh    = (const float*)d_in[6];
    const float* Ww    = (const float*)d_in[7];
    const float* gw    = (const float*)d_in[8];
    const float* bw    = (const float*)d_in[9];
    const float* fc0_w = (const float*)d_in[10];
    const float* fc0_b = (const float*)d_in[11];
    const float* bn1_g = (const float*)d_in[12];
    const float* bn1_b = (const float*)d_in[13];
    const float* fc1_w = (const float*)d_in[14];
    const float* fc1_b = (const float*)d_in[15];
    float* out = (float*)d_out;

    float* ws = (float*)d_ws;
    float* yp = ws;                  // [32][384][128]  1,572,864 floats
    float* y  = ws + 1572864;        // [32][384][128]
    float* hw = ws + 3145728;        // [32][384][128]  (xh | xw)
    float* z2 = ws + 4718592;        // [32][384]

    kpool<<<dim3(12288), dim3(256), 0, stream>>>(x, yp);
    kcbr<<<dim3(6, 4, 32), dim3(512), 0, stream>>>(yp, Wy, gy, by, Wy, gy, by, y);
    kcbr<<<dim3(6, 4, 32), dim3(512), 0, stream>>>(y, Wh, gh, bh, Ww, gw, bw, hw);
    kgate<<<dim3(32), dim3(256), 0, stream>>>(y, fc0_w, fc0_b, bn1_g, bn1_b, fc1_w, fc1_b, z2);
    kfinal<<<dim3(2048), dim3(256), 0, stream>>>(x, hw, z2, out);
}

// Round 2
// 168.560 us; speedup vs baseline: 1.1928x; 1.1928x over previous
//
#include <hip/hip_runtime.h>
#include <math.h>

#define RSQ 0.99999500003749975f  // 1/sqrt(1+1e-5)

// ---------------------------------------------------------------------------
// Kernel 1: CoordPooling (blocks 0..12287) + W pre-transpose (108 tail blocks).
// yp[bc][0:64]  = mean over w (per h);  yp[bc][64:128] = mean over h (per w)
// Wt[m][c][o] = W[m][o][c] for the three 384x384 conv weights.
// ---------------------------------------------------------------------------
__global__ __launch_bounds__(256) void kpool(const float* __restrict__ x,
                                             const float* __restrict__ Wy,
                                             const float* __restrict__ Wh,
                                             const float* __restrict__ Ww,
                                             float* __restrict__ yp,
                                             float* __restrict__ Wt) {
    __shared__ float sm[4352];
    int bid = blockIdx.x;
    int t = threadIdx.x;
    if (bid >= 12288) {
        // transpose one 64x64 tile; 36 tiles per matrix, 3 matrices
        float (*T)[65] = reinterpret_cast<float (*)[65]>(sm);
        int e0 = bid - 12288;
        int m = e0 / 36, rem = e0 % 36;
        int to = rem / 6, tc = rem % 6;
        const float* W = (m == 0) ? Wy : (m == 1) ? Wh : Ww;
        float* D = Wt + (size_t)m * 147456;
        int o0 = to * 64, c0 = tc * 64;
#pragma unroll
        for (int i = 0; i < 16; ++i) {
            int e = t + i * 256;
            int r = e >> 6, cl = e & 63;
            T[r][cl] = W[(size_t)(o0 + r) * 384 + c0 + cl];
        }
        __syncthreads();
#pragma unroll
        for (int i = 0; i < 16; ++i) {
            int e = t + i * 256;
            int r = e >> 6, cl = e & 63;
            D[(size_t)(c0 + r) * 384 + o0 + cl] = T[cl][r];
        }
        return;
    }
    float* pl = sm;          // [4096] plane
    float* part = sm + 4096; // [256]
    const float4* xp = reinterpret_cast<const float4*>(x) + (size_t)bid * 1024;
    float4* pl4 = reinterpret_cast<float4*>(pl);
#pragma unroll
    for (int k = 0; k < 4; ++k) pl4[k * 256 + t] = xp[k * 256 + t];
    __syncthreads();
    int lane = t & 63, pt = t >> 6;
    float rs = 0.f;
#pragma unroll
    for (int j = 0; j < 16; ++j) {
        int w = (pt * 16 + j + lane) & 63;  // rotate to dodge stride-64 banks
        rs += pl[lane * 64 + w];
    }
    part[t] = rs;
    __syncthreads();
    if (t < 64) {
        float v = part[t] + part[t + 64] + part[t + 128] + part[t + 192];
        yp[(size_t)bid * 128 + t] = v * 0.015625f;
    }
    __syncthreads();
    float cs = 0.f;
#pragma unroll
    for (int j = 0; j < 16; ++j) cs += pl[(pt * 16 + j) * 64 + lane];
    part[t] = cs;
    __syncthreads();
    if (t < 64) {
        float v = part[t] + part[t + 64] + part[t + 128] + part[t + 192];
        yp[(size_t)bid * 128 + 64 + t] = v * 0.015625f;
    }
}

// ---------------------------------------------------------------------------
// Kernels 2&3: CBR 1x1 conv GEMM, 64o x 32l tile, 128 threads, 4x4 reg tile.
// Blocks >= 768 (pass 2 only): SFP gate chain reading `in` (= y).
// ---------------------------------------------------------------------------
__global__ __launch_bounds__(128) void kcbr(const float* __restrict__ in,
    const float* __restrict__ Wt0, const float* __restrict__ g0, const float* __restrict__ b0,
    const float* __restrict__ Wt1, const float* __restrict__ g1, const float* __restrict__ b1,
    float* __restrict__ out,
    const float* __restrict__ fc0_w, const float* __restrict__ fc0_b,
    const float* __restrict__ bn1_g, const float* __restrict__ bn1_b,
    const float* __restrict__ fc1_w, const float* __restrict__ fc1_b,
    float* __restrict__ z2) {
    int bid = blockIdx.x;
    int t = threadIdx.x;
    if (bid >= 768) {
        // ---- gate: wavelet(==scaled channel mean) -> FC -> BN/ReLU -> FC ----
        __shared__ float z0[384];
        __shared__ float z1[24];
        int b = bid - 768;
        const float* yb = in + (size_t)b * 49152;
        for (int c = t; c < 384; c += 128) {
            const float4* r4 = reinterpret_cast<const float4*>(yb + (size_t)c * 128);
            float s = 0.f;
#pragma unroll
            for (int j = 0; j < 32; ++j) { float4 v = r4[j]; s += (v.x + v.y) + (v.z + v.w); }
            float fac = (c < 128) ? 1.41421356237310f : (c < 256 ? 2.0f : 2.82842712474619f);
            z0[c] = s * (fac * 0.0078125f);
        }
        __syncthreads();
        if (t < 96) {
            int r = t >> 2, j = t & 3;
            float p = 0.f;
            for (int c = j; c < 384; c += 4) p = fmaf(z0[c], fc0_w[r * 384 + c], p);
            p += __shfl_xor(p, 1);
            p += __shfl_xor(p, 2);
            if (j == 0) z1[r] = fmaxf(fmaf(p + fc0_b[r], bn1_g[r] * RSQ, bn1_b[r]), 0.f);
        }
        __syncthreads();
        for (int c = t; c < 384; c += 128) {
            float a = fc1_b[c];
#pragma unroll
            for (int r = 0; r < 24; ++r) a = fmaf(z1[r], fc1_w[c * 24 + r], a);
            z2[b * 384 + c] = a;
        }
        return;
    }
    // ---- GEMM ----
    __shared__ float Wl[32][68];  // [cc][o_rel], rows 16B-aligned
    __shared__ float Yl[32][36];  // [cc][l_rel]
    int ot = bid % 6;
    int lt = (bid / 6) % 4;
    int b  = bid / 24;
    int o0 = ot * 64, l0 = lt * 32;
    const float* Wt = (lt >= 2) ? Wt1 : Wt0;
    const float* g  = (lt >= 2) ? g1 : g0;
    const float* bb = (lt >= 2) ? b1 : b0;
    int lg = t & 7, og = t >> 3;  // l = l0+lg*4, o = o0+og*4
    const float* inb = in + (size_t)b * 49152 + l0;
    float acc[4][4];
#pragma unroll
    for (int i = 0; i < 4; ++i)
#pragma unroll
        for (int j = 0; j < 4; ++j) acc[i][j] = 0.f;

    auto ldW = [&](int c0, int i) {
        int idx = t + i * 128;
        int cc = idx >> 4, o4 = idx & 15;
        return *reinterpret_cast<const float4*>(Wt + (size_t)(c0 + cc) * 384 + o0 + o4 * 4);
    };
    auto ldY = [&](int c0, int i) {
        int idx = t + i * 128;
        int cc = idx >> 3, f4 = idx & 7;
        return *reinterpret_cast<const float4*>(inb + (size_t)(c0 + cc) * 128 + f4 * 4);
    };
    float4 wr0 = ldW(0, 0), wr1 = ldW(0, 1), wr2 = ldW(0, 2), wr3 = ldW(0, 3);
    float4 yr0 = ldY(0, 0), yr1 = ldY(0, 1);

    for (int ch = 0; ch < 12; ++ch) {
        if (ch) __syncthreads();
        *reinterpret_cast<float4*>(&Wl[t >> 4][(t & 15) * 4]) = wr0;
        *reinterpret_cast<float4*>(&Wl[(t + 128) >> 4][((t + 128) & 15) * 4]) = wr1;
        *reinterpret_cast<float4*>(&Wl[(t + 256) >> 4][((t + 256) & 15) * 4]) = wr2;
        *reinterpret_cast<float4*>(&Wl[(t + 384) >> 4][((t + 384) & 15) * 4]) = wr3;
        *reinterpret_cast<float4*>(&Yl[t >> 3][(t & 7) * 4]) = yr0;
        *reinterpret_cast<float4*>(&Yl[(t + 128) >> 3][((t + 128) & 7) * 4]) = yr1;
        __syncthreads();
        if (ch < 11) {
            int c0 = (ch + 1) * 32;
            wr0 = ldW(c0, 0); wr1 = ldW(c0, 1); wr2 = ldW(c0, 2); wr3 = ldW(c0, 3);
            yr0 = ldY(c0, 0); yr1 = ldY(c0, 1);
        }
#pragma unroll
        for (int cc = 0; cc < 32; ++cc) {
            const float4 wv = *reinterpret_cast<const float4*>(&Wl[cc][og * 4]);
            const float4 yv = *reinterpret_cast<const float4*>(&Yl[cc][lg * 4]);
            acc[0][0] = fmaf(wv.x, yv.x, acc[0][0]);
            acc[0][1] = fmaf(wv.x, yv.y, acc[0][1]);
            acc[0][2] = fmaf(wv.x, yv.z, acc[0][2]);
            acc[0][3] = fmaf(wv.x, yv.w, acc[0][3]);
            acc[1][0] = fmaf(wv.y, yv.x, acc[1][0]);
            acc[1][1] = fmaf(wv.y, yv.y, acc[1][1]);
            acc[1][2] = fmaf(wv.y, yv.z, acc[1][2]);
            acc[1][3] = fmaf(wv.y, yv.w, acc[1][3]);
            acc[2][0] = fmaf(wv.z, yv.x, acc[2][0]);
            acc[2][1] = fmaf(wv.z, yv.y, acc[2][1]);
            acc[2][2] = fmaf(wv.z, yv.z, acc[2][2]);
            acc[2][3] = fmaf(wv.z, yv.w, acc[2][3]);
            acc[3][0] = fmaf(wv.w, yv.x, acc[3][0]);
            acc[3][1] = fmaf(wv.w, yv.y, acc[3][1]);
            acc[3][2] = fmaf(wv.w, yv.z, acc[3][2]);
            acc[3][3] = fmaf(wv.w, yv.w, acc[3][3]);
        }
    }
#pragma unroll
    for (int i = 0; i < 4; ++i) {
        int o = o0 + og * 4 + i;
        float gg = g[o] * RSQ, bv = bb[o];
        float4 r;
        r.x = fmaxf(fmaf(acc[i][0], gg, bv), 0.f);
        r.y = fmaxf(fmaf(acc[i][1], gg, bv), 0.f);
        r.z = fmaxf(fmaf(acc[i][2], gg, bv), 0.f);
        r.w = fmaxf(fmaf(acc[i][3], gg, bv), 0.f);
        *reinterpret_cast<float4*>(&out[((size_t)b * 384 + o) * 128 + l0 + lg * 4]) = r;
    }
}

// ---------------------------------------------------------------------------
// Kernel 4: out = x * (sigmoid(xh[b,c,h]*xw[b,c,w]) + z2[b,c])
// hw layout: [b][c][128]: first 64 = xh row, last 64 = xw row.
// ---------------------------------------------------------------------------
__global__ __launch_bounds__(256) void kfinal(const float* __restrict__ x,
    const float* __restrict__ hw, const float* __restrict__ z2,
    float* __restrict__ out) {
    const float4* x4 = reinterpret_cast<const float4*>(x);
    float4* o4 = reinterpret_cast<float4*>(out);
    const int total4 = 12582912;  // 32*384*64*64/4
    int stride = gridDim.x * blockDim.x;
    for (int idx = blockIdx.x * blockDim.x + threadIdx.x; idx < total4; idx += stride) {
        int w4 = idx & 15;
        int h  = (idx >> 4) & 63;
        int bc = idx >> 10;
        float4 xv = x4[idx];
        float  a  = hw[(bc << 7) + h];
        const float4 wv = reinterpret_cast<const float4*>(hw)[(bc << 5) + 16 + w4];
        float  zv = z2[bc];
        float4 ov;
        ov.x = xv.x * (1.f / (1.f + __expf(-a * wv.x)) + zv);
        ov.y = xv.y * (1.f / (1.f + __expf(-a * wv.y)) + zv);
        ov.z = xv.z * (1.f / (1.f + __expf(-a * wv.z)) + zv);
        ov.w = xv.w * (1.f / (1.f + __expf(-a * wv.w)) + zv);
        o4[idx] = ov;
    }
}

// ---------------------------------------------------------------------------
extern "C" void kernel_launch(void* const* d_in, const int* in_sizes, int n_in,
                              void* d_out, int out_size, void* d_ws, size_t ws_size,
                              hipStream_t stream) {
    const float* x     = (const float*)d_in[0];
    const float* Wy    = (const float*)d_in[1];
    const float* gy    = (const float*)d_in[2];
    const float* by    = (const float*)d_in[3];
    const float* Wh    = (const float*)d_in[4];
    const float* gh    = (const float*)d_in[5];
    const float* bh    = (const float*)d_in[6];
    const float* Ww    = (const float*)d_in[7];
    const float* gw    = (const float*)d_in[8];
    const float* bw    = (const float*)d_in[9];
    const float* fc0_w = (const float*)d_in[10];
    const float* fc0_b = (const float*)d_in[11];
    const float* bn1_g = (const float*)d_in[12];
    const float* bn1_b = (const float*)d_in[13];
    const float* fc1_w = (const float*)d_in[14];
    const float* fc1_b = (const float*)d_in[15];
    float* out = (float*)d_out;

    float* ws = (float*)d_ws;
    float* yp = ws;                  // [32][384][128]
    float* y  = ws + 1572864;        // [32][384][128]
    float* hw = ws + 3145728;        // [32][384][128]  (xh | xw)
    float* z2 = ws + 4718592;        // [32][384]
    float* Wt = ws + 4730880;        // 3 x [384][384] transposed weights

    kpool<<<dim3(12288 + 108), dim3(256), 0, stream>>>(x, Wy, Wh, Ww, yp, Wt);
    kcbr<<<dim3(768), dim3(128), 0, stream>>>(yp, Wt, gy, by, Wt, gy, by, y,
        fc0_w, fc0_b, bn1_g, bn1_b, fc1_w, fc1_b, z2);
    kcbr<<<dim3(800), dim3(128), 0, stream>>>(y, Wt + 147456, gh, bh, Wt + 294912, gw, bw, hw,
        fc0_w, fc0_b, bn1_g, bn1_b, fc1_w, fc1_b, z2);
    kfinal<<<dim3(2048), dim3(256), 0, stream>>>(x, hw, z2, out);
}

// Round 4
// 138.236 us; speedup vs baseline: 1.4544x; 1.2194x over previous
//
#include <hip/hip_runtime.h>
#include <math.h>

#define RSQ 0.99999500003749975f  // 1/sqrt(1+1e-5)

typedef __attribute__((ext_vector_type(8))) __bf16 bf16x8;
typedef __attribute__((ext_vector_type(4))) float f32x4;
typedef __attribute__((ext_vector_type(4))) unsigned int u32x4;
typedef __attribute__((ext_vector_type(2))) unsigned int u32x2;

__device__ __forceinline__ unsigned short bfb(float v) {
    return __builtin_bit_cast(unsigned short, (__bf16)v);
}
__device__ __forceinline__ float bff(unsigned short u) {
    unsigned int x = ((unsigned int)u) << 16;
    return __builtin_bit_cast(float, x);
}

// ---------------------------------------------------------------------------
// Kernel 1: CoordPooling (blocks 0..12287, bf16 output) + W fragment-packing
// (72 tail blocks). Packed layout: region (m, ot16, cs32) = 64 lanes x 8 bf16,
// element (lane,i) = W[ot*16 + (lane&15)][cs*32 + (lane>>4)*8 + i].
// ---------------------------------------------------------------------------
__global__ __launch_bounds__(256) void kpool(const float* __restrict__ x,
                                             const float* __restrict__ Wy,
                                             const float* __restrict__ Wh,
                                             const float* __restrict__ Ww,
                                             unsigned short* __restrict__ ypb,
                                             unsigned short* __restrict__ Wp) {
    __shared__ float sm[6208];
    int bid = blockIdx.x;
    int t = threadIdx.x;
    if (bid >= 12288) {
        // ---- pack one 16o x 384c slab of one weight matrix ----
        int e = bid - 12288;
        int m = e / 24, ot = e % 24;
        const float* W = (m == 0) ? Wy : (m == 1) ? Wh : Ww;
        // load 16 rows x 384 cols into LDS, padded stride 388
#pragma unroll
        for (int k = 0; k < 6; ++k) {
            int idx = t + k * 256;          // over 1536 float4
            int r = idx / 96, c4 = idx % 96;
            f32x4 v = *reinterpret_cast<const f32x4*>(W + (size_t)(ot * 16 + r) * 384 + c4 * 4);
            *reinterpret_cast<f32x4*>(&sm[r * 388 + c4 * 4]) = v;
        }
        __syncthreads();
#pragma unroll
        for (int k = 0; k < 3; ++k) {
            int idx = t + k * 256;          // over 768 = 12 cs x 64 lanes
            int cs = idx >> 6, j = idx & 63;
            const float* src = &sm[(j & 15) * 388 + cs * 32 + (j >> 4) * 8];
            u32x4 pk;
            pk.x = (unsigned int)bfb(src[0]) | ((unsigned int)bfb(src[1]) << 16);
            pk.y = (unsigned int)bfb(src[2]) | ((unsigned int)bfb(src[3]) << 16);
            pk.z = (unsigned int)bfb(src[4]) | ((unsigned int)bfb(src[5]) << 16);
            pk.w = (unsigned int)bfb(src[6]) | ((unsigned int)bfb(src[7]) << 16);
            *reinterpret_cast<u32x4*>(Wp + ((size_t)(m * 24 + ot) * 12 + cs) * 512 + j * 8) = pk;
        }
        return;
    }
    float* pl = sm;          // [4096] plane
    float* part = sm + 4096; // [256]
    const f32x4* xp = reinterpret_cast<const f32x4*>(x) + (size_t)bid * 1024;
    f32x4* pl4 = reinterpret_cast<f32x4*>(pl);
#pragma unroll
    for (int k = 0; k < 4; ++k) pl4[k * 256 + t] = __builtin_nontemporal_load(xp + k * 256 + t);
    __syncthreads();
    int lane = t & 63, pt = t >> 6;
    float rs = 0.f;
#pragma unroll
    for (int j = 0; j < 16; ++j) {
        int w = (pt * 16 + j + lane) & 63;  // rotate to dodge stride-64 banks
        rs += pl[lane * 64 + w];
    }
    part[t] = rs;
    __syncthreads();
    if (t < 64) {
        float v = part[t] + part[t + 64] + part[t + 128] + part[t + 192];
        ypb[(size_t)bid * 128 + t] = bfb(v * 0.015625f);
    }
    __syncthreads();
    float cs = 0.f;
#pragma unroll
    for (int j = 0; j < 16; ++j) cs += pl[(pt * 16 + j) * 64 + lane];
    part[t] = cs;
    __syncthreads();
    if (t < 64) {
        float v = part[t] + part[t + 64] + part[t + 128] + part[t + 192];
        ypb[(size_t)bid * 128 + 64 + t] = bfb(v * 0.015625f);
    }
}

// ---------------------------------------------------------------------------
// Kernels 2&3: CBR 1x1 conv via bf16 MFMA. 256 thr = 4 waves, tile 64o x 32l,
// grid 768 = 3 blocks/CU. Wave w owns o-sub-tile w (16 o), two 16-l fragments.
// Blocks >= 768 (pass 2 only): SFP gate chain reading in16 (= y, bf16).
// ---------------------------------------------------------------------------
__global__ __launch_bounds__(256) void kcbr(const unsigned short* __restrict__ in16,
    const unsigned short* __restrict__ Wp,
    const float* __restrict__ g0, const float* __restrict__ b0,
    const float* __restrict__ g1, const float* __restrict__ b1,
    int m_lo, int m_hi,
    unsigned short* __restrict__ outb, float* __restrict__ outf,
    const float* __restrict__ fc0_w, const float* __restrict__ fc0_b,
    const float* __restrict__ bn1_g, const float* __restrict__ bn1_b,
    const float* __restrict__ fc1_w, const float* __restrict__ fc1_b,
    float* __restrict__ z2) {
    int bid = blockIdx.x;
    int t = threadIdx.x;
    if (bid >= 768) {
        // ---- gate: wavelet(==scaled channel mean) -> FC -> BN/ReLU -> FC ----
        __shared__ float z0[384];
        __shared__ float z1[24];
        int b = bid - 768;
        const unsigned short* yb = in16 + (size_t)b * 49152;
        for (int c = t; c < 384; c += 256) {
            const u32x4* r4 = reinterpret_cast<const u32x4*>(yb + (size_t)c * 128);
            float s = 0.f;
#pragma unroll
            for (int j = 0; j < 16; ++j) {
                u32x4 v = r4[j];
                s += bff((unsigned short)(v.x & 0xffff)) + bff((unsigned short)(v.x >> 16));
                s += bff((unsigned short)(v.y & 0xffff)) + bff((unsigned short)(v.y >> 16));
                s += bff((unsigned short)(v.z & 0xffff)) + bff((unsigned short)(v.z >> 16));
                s += bff((unsigned short)(v.w & 0xffff)) + bff((unsigned short)(v.w >> 16));
            }
            float fac = (c < 128) ? 1.41421356237310f : (c < 256 ? 2.0f : 2.82842712474619f);
            z0[c] = s * (fac * 0.0078125f);
        }
        __syncthreads();
        if (t < 96) {
            int r = t >> 2, j = t & 3;
            float p = 0.f;
            for (int c = j; c < 384; c += 4) p = fmaf(z0[c], fc0_w[r * 384 + c], p);
            p += __shfl_xor(p, 1);
            p += __shfl_xor(p, 2);
            if (j == 0) z1[r] = fmaxf(fmaf(p + fc0_b[r], bn1_g[r] * RSQ, bn1_b[r]), 0.f);
        }
        __syncthreads();
        for (int c = t; c < 384; c += 256) {
            float a = fc1_b[c];
#pragma unroll
            for (int r = 0; r < 24; ++r) a = fmaf(z1[r], fc1_w[c * 24 + r], a);
            z2[b * 384 + c] = a;
        }
        return;
    }
    // ---- MFMA GEMM ----
    __shared__ unsigned short As[2048];  // 4 regions x 64 lanes x 8 (o-frag packed)
    __shared__ unsigned short Bs[1024];  // [cg][l][8]
    int ot = bid % 6;
    int lt = (bid / 6) % 4;
    int b  = bid / 24;
    int o0 = ot * 64, l0 = lt * 32;
    int m = (lt >= 2) ? m_hi : m_lo;
    const float* g  = (lt >= 2) ? g1 : g0;
    const float* bb = (lt >= 2) ? b1 : b0;
    int w = t >> 6, lane = t & 63;
    const unsigned short* Asrc = Wp + ((size_t)(m * 24 + ot * 4 + w) * 12) * 512 + (size_t)lane * 8;
    int cB = t >> 3, l4 = (t & 7) * 4;
    const unsigned short* Bsrc = in16 + (size_t)b * 49152 + (size_t)cB * 128 + l0 + l4;
    unsigned short* BsW = &Bs[(cB >> 3) * 256 + (cB & 7)];

    u32x4 ar = *reinterpret_cast<const u32x4*>(Asrc);
    u32x2 br = *reinterpret_cast<const u32x2*>(Bsrc);
    f32x4 acc0 = {0.f, 0.f, 0.f, 0.f};
    f32x4 acc1 = {0.f, 0.f, 0.f, 0.f};

    for (int ch = 0; ch < 12; ++ch) {
        if (ch) __syncthreads();
        *reinterpret_cast<u32x4*>(&As[t * 8]) = ar;
        BsW[(l4 + 0) * 8] = (unsigned short)(br.x & 0xffff);
        BsW[(l4 + 1) * 8] = (unsigned short)(br.x >> 16);
        BsW[(l4 + 2) * 8] = (unsigned short)(br.y & 0xffff);
        BsW[(l4 + 3) * 8] = (unsigned short)(br.y >> 16);
        __syncthreads();
        if (ch < 11) {
            ar = *reinterpret_cast<const u32x4*>(Asrc + (ch + 1) * 512);
            br = *reinterpret_cast<const u32x2*>(Bsrc + (ch + 1) * 4096);
        }
        bf16x8 av  = *reinterpret_cast<const bf16x8*>(&As[w * 512 + lane * 8]);
        bf16x8 bv0 = *reinterpret_cast<const bf16x8*>(&Bs[(lane >> 4) * 256 + (lane & 15) * 8]);
        bf16x8 bv1 = *reinterpret_cast<const bf16x8*>(&Bs[(lane >> 4) * 256 + 128 + (lane & 15) * 8]);
        acc0 = __builtin_amdgcn_mfma_f32_16x16x32_bf16(av, bv0, acc0, 0, 0, 0);
        acc1 = __builtin_amdgcn_mfma_f32_16x16x32_bf16(av, bv1, acc1, 0, 0, 0);
    }
    int oB = o0 + w * 16 + (lane >> 4) * 4;
    int lB = l0 + (lane & 15);
    if (outb) {
#pragma unroll
        for (int r = 0; r < 4; ++r) {
            int o = oB + r;
            float sc = g[o] * RSQ, bi = bb[o];
            size_t base = ((size_t)b * 384 + o) * 128 + lB;
            outb[base]      = bfb(fmaxf(fmaf(acc0[r], sc, bi), 0.f));
            outb[base + 16] = bfb(fmaxf(fmaf(acc1[r], sc, bi), 0.f));
        }
    } else {
#pragma unroll
        for (int r = 0; r < 4; ++r) {
            int o = oB + r;
            float sc = g[o] * RSQ, bi = bb[o];
            size_t base = ((size_t)b * 384 + o) * 128 + lB;
            outf[base]      = fmaxf(fmaf(acc0[r], sc, bi), 0.f);
            outf[base + 16] = fmaxf(fmaf(acc1[r], sc, bi), 0.f);
        }
    }
}

// ---------------------------------------------------------------------------
// Kernel 4: out = x * (sigmoid(xh[b,c,h]*xw[b,c,w]) + z2[b,c])
// hw layout: [b][c][128] f32: first 64 = xh row, last 64 = xw row.
// ---------------------------------------------------------------------------
__global__ __launch_bounds__(256) void kfinal(const float* __restrict__ x,
    const float* __restrict__ hw, const float* __restrict__ z2,
    float* __restrict__ out) {
    const f32x4* x4 = reinterpret_cast<const f32x4*>(x);
    f32x4* o4 = reinterpret_cast<f32x4*>(out);
    const int total4 = 12582912;  // 32*384*64*64/4
    int stride = gridDim.x * blockDim.x;
    for (int idx = blockIdx.x * blockDim.x + threadIdx.x; idx < total4; idx += stride) {
        int w4 = idx & 15;
        int h  = (idx >> 4) & 63;
        int bc = idx >> 10;
        f32x4 xv = __builtin_nontemporal_load(x4 + idx);
        float  a  = hw[(bc << 7) + h];
        const f32x4 wv = reinterpret_cast<const f32x4*>(hw)[(bc << 5) + 16 + w4];
        float  zv = z2[bc];
        f32x4 ov;
        ov.x = xv.x * (1.f / (1.f + __expf(-a * wv.x)) + zv);
        ov.y = xv.y * (1.f / (1.f + __expf(-a * wv.y)) + zv);
        ov.z = xv.z * (1.f / (1.f + __expf(-a * wv.z)) + zv);
        ov.w = xv.w * (1.f / (1.f + __expf(-a * wv.w)) + zv);
        __builtin_nontemporal_store(ov, o4 + idx);
    }
}

// ---------------------------------------------------------------------------
extern "C" void kernel_launch(void* const* d_in, const int* in_sizes, int n_in,
                              void* d_out, int out_size, void* d_ws, size_t ws_size,
                              hipStream_t stream) {
    const float* x     = (const float*)d_in[0];
    const float* Wy    = (const float*)d_in[1];
    const float* gy    = (const float*)d_in[2];
    const float* by    = (const float*)d_in[3];
    const float* Wh    = (const float*)d_in[4];
    const float* gh    = (const float*)d_in[5];
    const float* bh    = (const float*)d_in[6];
    const float* Ww    = (const float*)d_in[7];
    const float* gw    = (const float*)d_in[8];
    const float* bw    = (const float*)d_in[9];
    const float* fc0_w = (const float*)d_in[10];
    const float* fc0_b = (const float*)d_in[11];
    const float* bn1_g = (const float*)d_in[12];
    const float* bn1_b = (const float*)d_in[13];
    const float* fc1_w = (const float*)d_in[14];
    const float* fc1_b = (const float*)d_in[15];
    float* out = (float*)d_out;

    char* ws = (char*)d_ws;
    unsigned short* ypb = (unsigned short*)ws;                    // [32][384][128] bf16
    unsigned short* yb  = (unsigned short*)(ws + 3145728);        // [32][384][128] bf16
    float*          hw  = (float*)(ws + 6291456);                 // [32][384][128] f32
    float*          z2  = (float*)(ws + 12582912);                // [32][384] f32
    unsigned short* Wp  = (unsigned short*)(ws + 12632064);       // 3x24x12x512 bf16 packed

    kpool<<<dim3(12288 + 72), dim3(256), 0, stream>>>(x, Wy, Wh, Ww, ypb, Wp);
    kcbr<<<dim3(768), dim3(256), 0, stream>>>(ypb, Wp, gy, by, gy, by, 0, 0, yb, nullptr,
        fc0_w, fc0_b, bn1_g, bn1_b, fc1_w, fc1_b, z2);
    kcbr<<<dim3(800), dim3(256), 0, stream>>>(yb, Wp, gh, bh, gw, bw, 1, 2, nullptr, hw,
        fc0_w, fc0_b, bn1_g, bn1_b, fc1_w, fc1_b, z2);
    kfinal<<<dim3(2048), dim3(256), 0, stream>>>(x, hw, z2, out);
}